// Round 16
// baseline (146.167 us; speedup 1.0000x reference)
//
#include <hip/hip_runtime.h>
#include <math.h>

#define NVEC 131072
#define DIM 64
#define KCB 512
#define FLT_BIG 3.402823466e38f

typedef __attribute__((ext_vector_type(8))) short bf16x8;
typedef __attribute__((ext_vector_type(4))) float f32x4;
typedef __attribute__((ext_vector_type(2))) float f32x2;

// d_out layout (floats): [0] loss | [1..8388608] quantized | [8388609] perplexity
//                        | [8388610 ..] encodings (131072 x 512)
// d_ws layout (bytes):
//   [0,2048)         u32 counts[512]
//   [2048]           float loss_acc
//   [4096,6144)      float norms[512]
//   [8192, +512K)    ushort e_bf2[32][4][64][8]  (tile, op{eh0,eh1,el0,el1}, lane, frag)
//   [532480, +512K)  int bi_idx[131072]

__device__ inline unsigned int bf16_rne(float f) {
    unsigned int u = __float_as_uint(f);
    u += 0x7fffu + ((u >> 16) & 1u);
    return u >> 16;
}

// merge two top-2 lists across lane groups (k-subsets are disjoint)
__device__ inline void merge_top2(float& d1, int& i1, float& d2, int& i2) {
#pragma unroll
    for (int m = 16; m <= 32; m <<= 1) {
        float e1 = __shfl_xor(d1, m), e2 = __shfl_xor(d2, m);
        int j1 = __shfl_xor(i1, m), j2 = __shfl_xor(i2, m);
        bool af = (d1 < e1) || (d1 == e1 && i1 < j1);
        float w2 = af ? d2 : e2; int w2i = af ? i2 : j2;   // winner's runner-up
        float lb = af ? e1 : d1; int lbi = af ? j1 : i1;   // loser's best
        bool bs = (w2 < lb) || (w2 == lb && w2i < lbi);
        d1 = af ? d1 : e1; i1 = af ? i1 : j1;
        d2 = bs ? w2 : lb; i2 = bs ? w2i : lbi;
    }
}

// prep: norms (fp32), fragment-ordered bf16 hi/lo codebook, zero counts/loss.
__global__ __launch_bounds__(256) void vq_prep(const float* __restrict__ emb,
                                               float* __restrict__ norms,
                                               unsigned short* __restrict__ e_bf2,
                                               unsigned int* __restrict__ counts,
                                               float* __restrict__ loss_acc) {
    int gid = blockIdx.x * 256 + threadIdx.x;   // 0..2047
    int tt = gid >> 6, l = gid & 63;
    int nl = l & 15, kg = l >> 4;
    int row = tt * 16 + nl;
    const float* e = emb + row * DIM + kg * 8;  // k-slice 0: kg*8..+8 ; slice 1: +32

    float4 p0 = ((const float4*)e)[0];
    float4 p1 = ((const float4*)e)[1];
    float4 q0 = ((const float4*)(e + 32))[0];
    float4 q1 = ((const float4*)(e + 32))[1];

    float f0[8] = {p0.x, p0.y, p0.z, p0.w, p1.x, p1.y, p1.z, p1.w};
    float f1[8] = {q0.x, q0.y, q0.z, q0.w, q1.x, q1.y, q1.z, q1.w};

    float s = 0.f;
#pragma unroll
    for (int j = 0; j < 8; ++j) s = fmaf(f0[j], f0[j], fmaf(f1[j], f1[j], s));
    s += __shfl_xor(s, 16);
    s += __shfl_xor(s, 32);
    if (kg == 0) norms[row] = s;

    union { bf16x8 v; unsigned int u[4]; } H0, H1, L0, L1;
#pragma unroll
    for (int j = 0; j < 4; ++j) {
        unsigned int h0a = bf16_rne(f0[2 * j]),     h0b = bf16_rne(f0[2 * j + 1]);
        unsigned int h1a = bf16_rne(f1[2 * j]),     h1b = bf16_rne(f1[2 * j + 1]);
        float r0a = f0[2 * j] - __uint_as_float(h0a << 16);
        float r0b = f0[2 * j + 1] - __uint_as_float(h0b << 16);
        float r1a = f1[2 * j] - __uint_as_float(h1a << 16);
        float r1b = f1[2 * j + 1] - __uint_as_float(h1b << 16);
        H0.u[j] = h0a | (h0b << 16);
        H1.u[j] = h1a | (h1b << 16);
        L0.u[j] = bf16_rne(r0a) | (bf16_rne(r0b) << 16);
        L1.u[j] = bf16_rne(r1a) | (bf16_rne(r1b) << 16);
    }
    unsigned short* dst = e_bf2 + (size_t)tt * 8192 + l * 8;
    *(bf16x8*)(dst)        = H0.v;   // eh0
    *(bf16x8*)(dst + 1024) = H1.v;   // eh1
    *(bf16x8*)(dst + 2048) = L0.v;   // el0
    *(bf16x8*)(dst + 3072) = L1.v;   // el1

    if (gid < KCB) counts[gid] = 0u;
    if (gid == 0) *loss_acc = 0.f;
}

// fused, parity role-split (post-coalescing retest of R11):
//  odd blocks  -> pure-store zero-fill of the 268MB encodings region
//  even blocks -> coalesced MFMA top-2 argmin + exact fp32 rescore +
//                 loss/hist/quantized; bi -> workspace (one-hot in vq_sfin,
//                 ordered by the kernel boundary — no device fences).
__global__ __launch_bounds__(256) void vq_fused(const float* __restrict__ x,
                                                const float* __restrict__ emb,
                                                const unsigned short* __restrict__ e_bf2,
                                                const float* __restrict__ norms,
                                                float* __restrict__ out,
                                                int* __restrict__ bi_out,
                                                unsigned int* __restrict__ counts,
                                                float* __restrict__ loss_acc) {
    float* __restrict__ qout = out + 1;
    float* __restrict__ enc  = out + 8388610;
    int b = blockIdx.x;
    int tid = threadIdx.x;

    if (b & 1) {
        // ---- fill role: pure stores, grid-strided sequential float4.
        // enc is 8B-aligned; enc+2 is 16B-aligned; head/tail float2 by block 1.
        f32x4* enc4 = (f32x4*)(enc + 2);
        int f = (b >> 1) * 256 + tid;        // 0..262143
        f32x4 z4 = {0.f, 0.f, 0.f, 0.f};
#pragma unroll 4
        for (int j = f; j < 16777215; j += 262144) enc4[j] = z4;
        if (b == 1 && tid == 0) { enc[0] = 0.f; enc[1] = 0.f; }
        if (b == 1 && tid == 1) { enc[67108862] = 0.f; enc[67108863] = 0.f; }
        return;
    }

    int cb = b >> 1;                        // 0..1023
    int wave = tid >> 6;
    int lane = tid & 63;
    int nl = lane & 15, kg = lane >> 4;
    int rowA = cb * 128 + wave * 32 + nl;
    int rowB = rowA + 16;

    __shared__ unsigned int hist[KCB];
    __shared__ int2 scand[128];
    __shared__ int sbi[128];
    __shared__ float serr[128];
    for (int j = tid; j < KCB; j += 256) hist[j] = 0u;

    // B-frags (x side): lane col = x-row, k = kg*8+e (+32 per kslice)
    bf16x8 xhA[2], xlA[2], xhB[2], xlB[2];
    {
        const float* xA = x + (size_t)rowA * DIM;
        const float* xB = x + (size_t)rowB * DIM;
#pragma unroll
        for (int ks = 0; ks < 2; ++ks) {
            const float4* pA = (const float4*)(xA + ks * 32 + kg * 8);
            const float4* pB = (const float4*)(xB + ks * 32 + kg * 8);
            float4 a0 = pA[0], a1 = pA[1], b0 = pB[0], b1 = pB[1];
            float fa[8] = {a0.x, a0.y, a0.z, a0.w, a1.x, a1.y, a1.z, a1.w};
            float fb[8] = {b0.x, b0.y, b0.z, b0.w, b1.x, b1.y, b1.z, b1.w};
            union { bf16x8 v; unsigned int u[4]; } HA, LA, HB, LB;
#pragma unroll
            for (int j = 0; j < 4; ++j) {
                unsigned int ha = bf16_rne(fa[2 * j]), hb = bf16_rne(fa[2 * j + 1]);
                unsigned int hc = bf16_rne(fb[2 * j]), hd = bf16_rne(fb[2 * j + 1]);
                float ra = fa[2 * j] - __uint_as_float(ha << 16);
                float rb = fa[2 * j + 1] - __uint_as_float(hb << 16);
                float rc = fb[2 * j] - __uint_as_float(hc << 16);
                float rd = fb[2 * j + 1] - __uint_as_float(hd << 16);
                HA.u[j] = ha | (hb << 16);
                LA.u[j] = bf16_rne(ra) | (bf16_rne(rb) << 16);
                HB.u[j] = hc | (hd << 16);
                LB.u[j] = bf16_rne(rc) | (bf16_rne(rd) << 16);
            }
            xhA[ks] = HA.v; xlA[ks] = LA.v;
            xhB[ks] = HB.v; xlB[ks] = LB.v;
        }
    }

    float d1A = FLT_BIG, d2A = FLT_BIG, d1B = FLT_BIG, d2B = FLT_BIG;
    int i1A = 0, i2A = 0, i1B = 0, i2B = 0;

    // stagger codebook tile order per block to decorrelate L2 pressure
    int t0 = cb & 31;
    const unsigned short* ebl = e_bf2 + (size_t)lane * 8;   // lane fragment base
#pragma unroll 2
    for (int t = 0; t < 32; ++t) {
        int tt = (t + t0) & 31;
        const unsigned short* eb = ebl + (size_t)tt * 8192;
        // contiguous 1KB wave loads (coalesced): op strides of 2KB
        bf16x8 eh0 = *(const bf16x8*)(eb);
        bf16x8 eh1 = *(const bf16x8*)(eb + 1024);
        bf16x8 el0 = *(const bf16x8*)(eb + 2048);
        bf16x8 el1 = *(const bf16x8*)(eb + 3072);

        // split accumulators per kslice: 4 independent 3-deep MFMA chains
        f32x4 aA0 = {}, aA1 = {}, aB0 = {}, aB1 = {};
        aA0 = __builtin_amdgcn_mfma_f32_16x16x32_bf16(eh0, xhA[0], aA0, 0, 0, 0);
        aA1 = __builtin_amdgcn_mfma_f32_16x16x32_bf16(eh1, xhA[1], aA1, 0, 0, 0);
        aB0 = __builtin_amdgcn_mfma_f32_16x16x32_bf16(eh0, xhB[0], aB0, 0, 0, 0);
        aB1 = __builtin_amdgcn_mfma_f32_16x16x32_bf16(eh1, xhB[1], aB1, 0, 0, 0);
        aA0 = __builtin_amdgcn_mfma_f32_16x16x32_bf16(el0, xhA[0], aA0, 0, 0, 0);
        aA1 = __builtin_amdgcn_mfma_f32_16x16x32_bf16(el1, xhA[1], aA1, 0, 0, 0);
        aB0 = __builtin_amdgcn_mfma_f32_16x16x32_bf16(el0, xhB[0], aB0, 0, 0, 0);
        aB1 = __builtin_amdgcn_mfma_f32_16x16x32_bf16(el1, xhB[1], aB1, 0, 0, 0);
        aA0 = __builtin_amdgcn_mfma_f32_16x16x32_bf16(eh0, xlA[0], aA0, 0, 0, 0);
        aA1 = __builtin_amdgcn_mfma_f32_16x16x32_bf16(eh1, xlA[1], aA1, 0, 0, 0);
        aB0 = __builtin_amdgcn_mfma_f32_16x16x32_bf16(eh0, xlB[0], aB0, 0, 0, 0);
        aB1 = __builtin_amdgcn_mfma_f32_16x16x32_bf16(eh1, xlB[1], aB1, 0, 0, 0);

        // C/D: col=lane&15 (x-row), row=(lane>>4)*4+reg (e-idx) [m89-verified]
        int krow0 = tt * 16 + kg * 4;
        f32x4 nv = *(const f32x4*)(norms + krow0);
#pragma unroll
        for (int r = 0; r < 4; ++r) {
            float en = nv[r];
            int ki = krow0 + r;
            float dA = fmaf(-2.f, aA0[r] + aA1[r], en);   // xn dropped: row-constant
            bool c1 = dA < d1A, c2 = dA < d2A;
            d2A = c1 ? d1A : (c2 ? dA : d2A);
            i2A = c1 ? i1A : (c2 ? ki : i2A);
            d1A = c1 ? dA : d1A;
            i1A = c1 ? ki : i1A;
            float dB = fmaf(-2.f, aB0[r] + aB1[r], en);
            bool e1c = dB < d1B, e2c = dB < d2B;
            d2B = e1c ? d1B : (e2c ? dB : d2B);
            i2B = e1c ? i1B : (e2c ? ki : i2B);
            d1B = e1c ? dB : d1B;
            i1B = e1c ? ki : i1B;
        }
    }

    merge_top2(d1A, i1A, d2A, i2A);
    merge_top2(d1B, i1B, d2B, i2B);
    if (lane < 16) {
        scand[wave * 32 + nl] = make_int2(i1A, i2A);
        scand[wave * 32 + nl + 16] = make_int2(i1B, i2B);
    }
    __syncthreads();

    // ---- exact fp32 rescore: one thread per row, STREAMED (low VGPR)
    if (tid < 128) {
        int grow = cb * 128 + tid;
        int2 cd = scand[tid];
        const float4* xr = (const float4*)(x + (size_t)grow * DIM);
        const float4* eA = (const float4*)(emb + (size_t)cd.x * DIM);
        const float4* eB = (const float4*)(emb + (size_t)cd.y * DIM);

        float n0 = 0.f, n1 = 0.f, n2 = 0.f, n3 = 0.f;
        float a0 = 0.f, a1 = 0.f, a2 = 0.f, a3 = 0.f;
        float b0 = 0.f, b1 = 0.f, b2 = 0.f, b3 = 0.f;
#pragma unroll
        for (int j = 0; j < 16; ++j) {
            float4 xv = xr[j];
            float4 ev = eA[j], fv = eB[j];
            n0 = fmaf(xv.x, xv.x, n0);
            n1 = fmaf(xv.y, xv.y, n1);
            n2 = fmaf(xv.z, xv.z, n2);
            n3 = fmaf(xv.w, xv.w, n3);
            a0 = fmaf(xv.x, ev.x, a0);
            a1 = fmaf(xv.y, ev.y, a1);
            a2 = fmaf(xv.z, ev.z, a2);
            a3 = fmaf(xv.w, ev.w, a3);
            b0 = fmaf(xv.x, fv.x, b0);
            b1 = fmaf(xv.y, fv.y, b1);
            b2 = fmaf(xv.z, fv.z, b2);
            b3 = fmaf(xv.w, fv.w, b3);
        }
        float xn = (n0 + n1) + (n2 + n3);
        float dotA = (a0 + a1) + (a2 + a3);
        float dotB = (b0 + b1) + (b2 + b3);
        float dA = fmaf(-2.f, dotA, xn) + norms[cd.x];
        float dB = fmaf(-2.f, dotB, xn) + norms[cd.y];
        // np.argmin keeps FIRST minimum -> ties to smaller index
        int bi = (dB < dA || (dB == dA && cd.y < cd.x)) ? cd.y : cd.x;

        // err pass: sum (x - e_bi)^2
        const float4* ebv = (const float4*)(emb + (size_t)bi * DIM);
        float c0 = 0.f, c1 = 0.f, c2 = 0.f, c3 = 0.f;
#pragma unroll
        for (int j = 0; j < 16; ++j) {
            float4 xv = xr[j];
            float4 ev = ebv[j];
            float e0 = xv.x - ev.x, e1 = xv.y - ev.y;
            float e2 = xv.z - ev.z, e3 = xv.w - ev.w;
            c0 = fmaf(e0, e0, c0);
            c1 = fmaf(e1, e1, c1);
            c2 = fmaf(e2, e2, c2);
            c3 = fmaf(e3, e3, c3);
        }
        float err = (c0 + c1) + (c2 + c3);

        sbi[tid] = bi;
        serr[tid] = err;
        atomicAdd(&hist[bi], 1u);
        bi_out[grow] = bi;          // one-hot deferred to vq_sfin
    }
    __syncthreads();

    // flush histogram
    for (int j = tid; j < KCB; j += 256) {
        unsigned int c = hist[j];
        if (c) atomicAdd(&counts[j], c);
    }
    // loss reduction over 128 row errors
    if (tid < 64) {
        float v = serr[tid] + serr[tid + 64];
#pragma unroll
        for (int off = 32; off > 0; off >>= 1) v += __shfl_down(v, off);
        if (tid == 0) atomicAdd(loss_acc, v);
    }
    // cooperative quantized write (dword stores; qout = out+1, 4B-aligned)
#pragma unroll 4
    for (int j = 0; j < 32; ++j) {
        int f = j * 256 + tid;          // 0..8191
        int r = f >> 6, c = f & 63;
        qout[((size_t)cb * 128 + r) * DIM + c] = emb[(size_t)sbi[r] * DIM + c];
    }
}

// one-hot scatter (ordered after fill/compute by kernel boundary) + finalize
__global__ __launch_bounds__(256) void vq_sfin(const int* __restrict__ bi_idx,
                                               const unsigned int* __restrict__ counts,
                                               const float* __restrict__ loss_acc,
                                               float* __restrict__ out) {
    float* __restrict__ enc = out + 8388610;
    int i = blockIdx.x * 256 + threadIdx.x;
    enc[(size_t)i * KCB + bi_idx[i]] = 1.0f;

    if (blockIdx.x == 0) {
        __shared__ float red[256];
        int t = threadIdx.x;
        float pa = (float)counts[t] * (1.0f / 131072.0f);
        float pb = (float)counts[t + 256] * (1.0f / 131072.0f);
        red[t] = pa * logf(pa + 1e-10f) + pb * logf(pb + 1e-10f);
        __syncthreads();
        for (int s = 128; s > 0; s >>= 1) {
            if (t < s) red[t] += red[t + s];
            __syncthreads();
        }
        if (t == 0) {
            out[8388609] = expf(-red[0]);
            out[0] = 1.25f * (*loss_acc) * (1.0f / 8388608.0f);
        }
    }
}

extern "C" void kernel_launch(void* const* d_in, const int* in_sizes, int n_in,
                              void* d_out, int out_size, void* d_ws, size_t ws_size,
                              hipStream_t stream) {
    const float* x   = (const float*)d_in[0];
    const float* emb = (const float*)d_in[1];
    float* out = (float*)d_out;
    char* ws = (char*)d_ws;
    unsigned int* counts = (unsigned int*)ws;
    float* loss_acc = (float*)(ws + 2048);
    float* norms = (float*)(ws + 4096);
    unsigned short* e_bf2 = (unsigned short*)(ws + 8192);
    int* bi_idx = (int*)(ws + 532480);

    vq_prep<<<8, 256, 0, stream>>>(emb, norms, e_bf2, counts, loss_acc);
    vq_fused<<<2048, 256, 0, stream>>>(x, emb, e_bf2, norms, out, bi_idx, counts, loss_acc);
    vq_sfin<<<512, 256, 0, stream>>>(bi_idx, counts, loss_acc, out);
}

// Round 17
// 110.772 us; speedup vs baseline: 1.3195x; 1.3195x over previous
//
#include <hip/hip_runtime.h>
#include <math.h>

#define NVEC 131072
#define DIM 64
#define KCB 512
#define FLT_BIG 3.402823466e38f

typedef __attribute__((ext_vector_type(8))) short bf16x8;
typedef __attribute__((ext_vector_type(4))) float f32x4;
typedef __attribute__((ext_vector_type(2))) float f32x2;

// d_out layout (floats): [0] loss | [1..8388608] quantized | [8388609] perplexity
//                        | [8388610 ..] encodings (131072 x 512)
// d_ws layout (bytes):
//   [0,2048)         u32 counts[512]
//   [2048]           float loss_acc
//   [4096,6144)      float norms[512]
//   [8192, +512K)    ushort e_bf2[32][4][64][8]  (tile, op{eh0,eh1,el0,el1}, lane, frag)
//                    -> every wave load is a contiguous 1KB (no gathers)

__device__ inline unsigned int bf16_rne(float f) {
    unsigned int u = __float_as_uint(f);
    u += 0x7fffu + ((u >> 16) & 1u);
    return u >> 16;
}

// merge two top-2 lists across lane groups (k-subsets are disjoint)
__device__ inline void merge_top2(float& d1, int& i1, float& d2, int& i2) {
#pragma unroll
    for (int m = 16; m <= 32; m <<= 1) {
        float e1 = __shfl_xor(d1, m), e2 = __shfl_xor(d2, m);
        int j1 = __shfl_xor(i1, m), j2 = __shfl_xor(i2, m);
        bool af = (d1 < e1) || (d1 == e1 && i1 < j1);
        float w2 = af ? d2 : e2; int w2i = af ? i2 : j2;   // winner's runner-up
        float lb = af ? e1 : d1; int lbi = af ? j1 : i1;   // loser's best
        bool bs = (w2 < lb) || (w2 == lb && w2i < lbi);
        d1 = af ? d1 : e1; i1 = af ? i1 : j1;
        d2 = bs ? w2 : lb; i2 = bs ? w2i : lbi;
    }
}

// prep: norms (fp32), fragment-ordered bf16 hi/lo codebook, zero counts/loss.
__global__ __launch_bounds__(256) void vq_prep(const float* __restrict__ emb,
                                               float* __restrict__ norms,
                                               unsigned short* __restrict__ e_bf2,
                                               unsigned int* __restrict__ counts,
                                               float* __restrict__ loss_acc) {
    int gid = blockIdx.x * 256 + threadIdx.x;   // 0..2047
    int tt = gid >> 6, l = gid & 63;
    int nl = l & 15, kg = l >> 4;
    int row = tt * 16 + nl;
    const float* e = emb + row * DIM + kg * 8;  // k-slice 0: kg*8..+8 ; slice 1: +32

    float4 p0 = ((const float4*)e)[0];
    float4 p1 = ((const float4*)e)[1];
    float4 q0 = ((const float4*)(e + 32))[0];
    float4 q1 = ((const float4*)(e + 32))[1];

    float f0[8] = {p0.x, p0.y, p0.z, p0.w, p1.x, p1.y, p1.z, p1.w};
    float f1[8] = {q0.x, q0.y, q0.z, q0.w, q1.x, q1.y, q1.z, q1.w};

    float s = 0.f;
#pragma unroll
    for (int j = 0; j < 8; ++j) s = fmaf(f0[j], f0[j], fmaf(f1[j], f1[j], s));
    s += __shfl_xor(s, 16);
    s += __shfl_xor(s, 32);
    if (kg == 0) norms[row] = s;

    union { bf16x8 v; unsigned int u[4]; } H0, H1, L0, L1;
#pragma unroll
    for (int j = 0; j < 4; ++j) {
        unsigned int h0a = bf16_rne(f0[2 * j]),     h0b = bf16_rne(f0[2 * j + 1]);
        unsigned int h1a = bf16_rne(f1[2 * j]),     h1b = bf16_rne(f1[2 * j + 1]);
        float r0a = f0[2 * j] - __uint_as_float(h0a << 16);
        float r0b = f0[2 * j + 1] - __uint_as_float(h0b << 16);
        float r1a = f1[2 * j] - __uint_as_float(h1a << 16);
        float r1b = f1[2 * j + 1] - __uint_as_float(h1b << 16);
        H0.u[j] = h0a | (h0b << 16);
        H1.u[j] = h1a | (h1b << 16);
        L0.u[j] = bf16_rne(r0a) | (bf16_rne(r0b) << 16);
        L1.u[j] = bf16_rne(r1a) | (bf16_rne(r1b) << 16);
    }
    unsigned short* dst = e_bf2 + (size_t)tt * 8192 + l * 8;
    *(bf16x8*)(dst)        = H0.v;   // eh0
    *(bf16x8*)(dst + 1024) = H1.v;   // eh1
    *(bf16x8*)(dst + 2048) = L0.v;   // el0
    *(bf16x8*)(dst + 3072) = L1.v;   // el1

    if (gid < KCB) counts[gid] = 0u;
    if (gid == 0) *loss_acc = 0.f;
}

// fused: pure-compute MFMA top-2 argmin; exact fp32 rescore; then each wave
// writes its 32 encodings rows ONCE as coalesced f32x2 with the one-hot
// embedded (no zero-pass + RMW, no cross-block ordering). Tiny vq_final after.
__global__ __launch_bounds__(256) void vq_fused(const float* __restrict__ x,
                                                const float* __restrict__ emb,
                                                const unsigned short* __restrict__ e_bf2,
                                                const float* __restrict__ norms,
                                                float* __restrict__ out,
                                                unsigned int* __restrict__ counts,
                                                float* __restrict__ loss_acc) {
    float* __restrict__ qout = out + 1;
    float* __restrict__ enc  = out + 8388610;
    int tid = threadIdx.x;
    int wave = tid >> 6;
    int lane = tid & 63;
    int nl = lane & 15, kg = lane >> 4;
    int rowA = blockIdx.x * 128 + wave * 32 + nl;
    int rowB = rowA + 16;

    __shared__ unsigned int hist[KCB];
    __shared__ int2 scand[128];
    __shared__ int sbi[128];
    __shared__ float serr[128];
    for (int j = tid; j < KCB; j += 256) hist[j] = 0u;

    // B-frags (x side): lane col = x-row, k = kg*8+e (+32 per kslice)
    bf16x8 xhA[2], xlA[2], xhB[2], xlB[2];
    {
        const float* xA = x + (size_t)rowA * DIM;
        const float* xB = x + (size_t)rowB * DIM;
#pragma unroll
        for (int ks = 0; ks < 2; ++ks) {
            const float4* pA = (const float4*)(xA + ks * 32 + kg * 8);
            const float4* pB = (const float4*)(xB + ks * 32 + kg * 8);
            float4 a0 = pA[0], a1 = pA[1], b0 = pB[0], b1 = pB[1];
            float fa[8] = {a0.x, a0.y, a0.z, a0.w, a1.x, a1.y, a1.z, a1.w};
            float fb[8] = {b0.x, b0.y, b0.z, b0.w, b1.x, b1.y, b1.z, b1.w};
            union { bf16x8 v; unsigned int u[4]; } HA, LA, HB, LB;
#pragma unroll
            for (int j = 0; j < 4; ++j) {
                unsigned int ha = bf16_rne(fa[2 * j]), hb = bf16_rne(fa[2 * j + 1]);
                unsigned int hc = bf16_rne(fb[2 * j]), hd = bf16_rne(fb[2 * j + 1]);
                float ra = fa[2 * j] - __uint_as_float(ha << 16);
                float rb = fa[2 * j + 1] - __uint_as_float(hb << 16);
                float rc = fb[2 * j] - __uint_as_float(hc << 16);
                float rd = fb[2 * j + 1] - __uint_as_float(hd << 16);
                HA.u[j] = ha | (hb << 16);
                LA.u[j] = bf16_rne(ra) | (bf16_rne(rb) << 16);
                HB.u[j] = hc | (hd << 16);
                LB.u[j] = bf16_rne(rc) | (bf16_rne(rd) << 16);
            }
            xhA[ks] = HA.v; xlA[ks] = LA.v;
            xhB[ks] = HB.v; xlB[ks] = LB.v;
        }
    }

    float d1A = FLT_BIG, d2A = FLT_BIG, d1B = FLT_BIG, d2B = FLT_BIG;
    int i1A = 0, i2A = 0, i1B = 0, i2B = 0;

    // stagger codebook tile order per block to decorrelate L2 pressure
    int t0 = blockIdx.x & 31;
    const unsigned short* ebl = e_bf2 + (size_t)lane * 8;   // lane fragment base
#pragma unroll 2
    for (int t = 0; t < 32; ++t) {
        int tt = (t + t0) & 31;
        const unsigned short* eb = ebl + (size_t)tt * 8192;
        // contiguous 1KB wave loads (coalesced): op strides of 2KB
        bf16x8 eh0 = *(const bf16x8*)(eb);
        bf16x8 eh1 = *(const bf16x8*)(eb + 1024);
        bf16x8 el0 = *(const bf16x8*)(eb + 2048);
        bf16x8 el1 = *(const bf16x8*)(eb + 3072);

        // split accumulators per kslice: 4 independent 3-deep MFMA chains
        f32x4 aA0 = {}, aA1 = {}, aB0 = {}, aB1 = {};
        aA0 = __builtin_amdgcn_mfma_f32_16x16x32_bf16(eh0, xhA[0], aA0, 0, 0, 0);
        aA1 = __builtin_amdgcn_mfma_f32_16x16x32_bf16(eh1, xhA[1], aA1, 0, 0, 0);
        aB0 = __builtin_amdgcn_mfma_f32_16x16x32_bf16(eh0, xhB[0], aB0, 0, 0, 0);
        aB1 = __builtin_amdgcn_mfma_f32_16x16x32_bf16(eh1, xhB[1], aB1, 0, 0, 0);
        aA0 = __builtin_amdgcn_mfma_f32_16x16x32_bf16(el0, xhA[0], aA0, 0, 0, 0);
        aA1 = __builtin_amdgcn_mfma_f32_16x16x32_bf16(el1, xhA[1], aA1, 0, 0, 0);
        aB0 = __builtin_amdgcn_mfma_f32_16x16x32_bf16(el0, xhB[0], aB0, 0, 0, 0);
        aB1 = __builtin_amdgcn_mfma_f32_16x16x32_bf16(el1, xhB[1], aB1, 0, 0, 0);
        aA0 = __builtin_amdgcn_mfma_f32_16x16x32_bf16(eh0, xlA[0], aA0, 0, 0, 0);
        aA1 = __builtin_amdgcn_mfma_f32_16x16x32_bf16(eh1, xlA[1], aA1, 0, 0, 0);
        aB0 = __builtin_amdgcn_mfma_f32_16x16x32_bf16(eh0, xlB[0], aB0, 0, 0, 0);
        aB1 = __builtin_amdgcn_mfma_f32_16x16x32_bf16(eh1, xlB[1], aB1, 0, 0, 0);

        // C/D: col=lane&15 (x-row), row=(lane>>4)*4+reg (e-idx) [m89-verified]
        int krow0 = tt * 16 + kg * 4;
        f32x4 nv = *(const f32x4*)(norms + krow0);
#pragma unroll
        for (int r = 0; r < 4; ++r) {
            float en = nv[r];
            int ki = krow0 + r;
            float dA = fmaf(-2.f, aA0[r] + aA1[r], en);   // xn dropped: row-constant
            bool c1 = dA < d1A, c2 = dA < d2A;
            d2A = c1 ? d1A : (c2 ? dA : d2A);
            i2A = c1 ? i1A : (c2 ? ki : i2A);
            d1A = c1 ? dA : d1A;
            i1A = c1 ? ki : i1A;
            float dB = fmaf(-2.f, aB0[r] + aB1[r], en);
            bool e1c = dB < d1B, e2c = dB < d2B;
            d2B = e1c ? d1B : (e2c ? dB : d2B);
            i2B = e1c ? i1B : (e2c ? ki : i2B);
            d1B = e1c ? dB : d1B;
            i1B = e1c ? ki : i1B;
        }
    }

    merge_top2(d1A, i1A, d2A, i2A);
    merge_top2(d1B, i1B, d2B, i2B);
    if (lane < 16) {
        scand[wave * 32 + nl] = make_int2(i1A, i2A);
        scand[wave * 32 + nl + 16] = make_int2(i1B, i2B);
    }
    __syncthreads();

    // ---- exact fp32 rescore: one thread per row, STREAMED (low VGPR)
    if (tid < 128) {
        int grow = blockIdx.x * 128 + tid;
        int2 cd = scand[tid];
        const float4* xr = (const float4*)(x + (size_t)grow * DIM);
        const float4* eA = (const float4*)(emb + (size_t)cd.x * DIM);
        const float4* eB = (const float4*)(emb + (size_t)cd.y * DIM);

        float n0 = 0.f, n1 = 0.f, n2 = 0.f, n3 = 0.f;
        float a0 = 0.f, a1 = 0.f, a2 = 0.f, a3 = 0.f;
        float b0 = 0.f, b1 = 0.f, b2 = 0.f, b3 = 0.f;
#pragma unroll
        for (int j = 0; j < 16; ++j) {
            float4 xv = xr[j];
            float4 ev = eA[j], fv = eB[j];
            n0 = fmaf(xv.x, xv.x, n0);
            n1 = fmaf(xv.y, xv.y, n1);
            n2 = fmaf(xv.z, xv.z, n2);
            n3 = fmaf(xv.w, xv.w, n3);
            a0 = fmaf(xv.x, ev.x, a0);
            a1 = fmaf(xv.y, ev.y, a1);
            a2 = fmaf(xv.z, ev.z, a2);
            a3 = fmaf(xv.w, ev.w, a3);
            b0 = fmaf(xv.x, fv.x, b0);
            b1 = fmaf(xv.y, fv.y, b1);
            b2 = fmaf(xv.z, fv.z, b2);
            b3 = fmaf(xv.w, fv.w, b3);
        }
        float xn = (n0 + n1) + (n2 + n3);
        float dotA = (a0 + a1) + (a2 + a3);
        float dotB = (b0 + b1) + (b2 + b3);
        float dA = fmaf(-2.f, dotA, xn) + norms[cd.x];
        float dB = fmaf(-2.f, dotB, xn) + norms[cd.y];
        // np.argmin keeps FIRST minimum -> ties to smaller index
        int bi = (dB < dA || (dB == dA && cd.y < cd.x)) ? cd.y : cd.x;

        // err pass: sum (x - e_bi)^2
        const float4* ebv = (const float4*)(emb + (size_t)bi * DIM);
        float c0 = 0.f, c1 = 0.f, c2 = 0.f, c3 = 0.f;
#pragma unroll
        for (int j = 0; j < 16; ++j) {
            float4 xv = xr[j];
            float4 ev = ebv[j];
            float e0 = xv.x - ev.x, e1 = xv.y - ev.y;
            float e2 = xv.z - ev.z, e3 = xv.w - ev.w;
            c0 = fmaf(e0, e0, c0);
            c1 = fmaf(e1, e1, c1);
            c2 = fmaf(e2, e2, c2);
            c3 = fmaf(e3, e3, c3);
        }
        float err = (c0 + c1) + (c2 + c3);

        sbi[tid] = bi;
        serr[tid] = err;
        atomicAdd(&hist[bi], 1u);
    }
    __syncthreads();

    // flush histogram
    for (int j = tid; j < KCB; j += 256) {
        unsigned int c = hist[j];
        if (c) atomicAdd(&counts[j], c);
    }
    // loss reduction over 128 row errors
    if (tid < 64) {
        float v = serr[tid] + serr[tid + 64];
#pragma unroll
        for (int off = 32; off > 0; off >>= 1) v += __shfl_down(v, off);
        if (tid == 0) atomicAdd(loss_acc, v);
    }

    // ---- single-pass encodings write with embedded one-hot.
    // Wave w owns rows [w*32, w*32+32): 8192 f32x2 slots, fully coalesced.
    // Each store instruction's 64 lanes stay within ONE row (64 slots < 256/row,
    // base aligned) -> sbi[lrow] is wave-uniform.
    {
        f32x2* enc2 = (f32x2*)enc;                       // enc is 8B-aligned
        size_t base_k = (size_t)blockIdx.x * 32768 + (size_t)wave * 8192;
#pragma unroll 4
        for (int s = 0; s < 128; ++s) {
            int lrow = wave * 32 + (s >> 2);             // 4 s-steps per row
            int w0 = (s & 3) * 128 + lane * 2;           // within-row float idx
            int bi = sbi[lrow];
            f32x2 v;
            v.x = (bi == w0) ? 1.f : 0.f;
            v.y = (bi == w0 + 1) ? 1.f : 0.f;
            enc2[base_k + s * 64 + lane] = v;
        }
    }

    // cooperative quantized write (dword stores; qout = out+1, 4B-aligned)
#pragma unroll 4
    for (int j = 0; j < 32; ++j) {
        int f = j * 256 + tid;          // 0..8191
        int r = f >> 6, c = f & 63;
        qout[((size_t)blockIdx.x * 128 + r) * DIM + c] =
            emb[(size_t)sbi[r] * DIM + c];
    }
}

__global__ __launch_bounds__(512) void vq_final(const unsigned int* __restrict__ counts,
                                                const float* __restrict__ loss_acc,
                                                float* __restrict__ out) {
    __shared__ float red[512];
    int t = threadIdx.x;
    float p = (float)counts[t] * (1.0f / 131072.0f);
    red[t] = p * logf(p + 1e-10f);
    __syncthreads();
    for (int s = 256; s > 0; s >>= 1) {
        if (t < s) red[t] += red[t + s];
        __syncthreads();
    }
    if (t == 0) {
        out[8388609] = expf(-red[0]);
        out[0] = 1.25f * (*loss_acc) * (1.0f / 8388608.0f);
    }
}

extern "C" void kernel_launch(void* const* d_in, const int* in_sizes, int n_in,
                              void* d_out, int out_size, void* d_ws, size_t ws_size,
                              hipStream_t stream) {
    const float* x   = (const float*)d_in[0];
    const float* emb = (const float*)d_in[1];
    float* out = (float*)d_out;
    char* ws = (char*)d_ws;
    unsigned int* counts = (unsigned int*)ws;
    float* loss_acc = (float*)(ws + 2048);
    float* norms = (float*)(ws + 4096);
    unsigned short* e_bf2 = (unsigned short*)(ws + 8192);

    vq_prep<<<8, 256, 0, stream>>>(emb, norms, e_bf2, counts, loss_acc);
    vq_fused<<<1024, 256, 0, stream>>>(x, emb, e_bf2, norms, out, counts, loss_acc);
    vq_final<<<1, 512, 0, stream>>>(counts, loss_acc, out);
}

// Round 18
// 89.996 us; speedup vs baseline: 1.6242x; 1.2309x over previous
//
#include <hip/hip_runtime.h>
#include <math.h>

#define NVEC 131072
#define DIM 64
#define KCB 512
#define FLT_BIG 3.402823466e38f

typedef __attribute__((ext_vector_type(8))) short bf16x8;
typedef __attribute__((ext_vector_type(4))) float f32x4;
typedef __attribute__((ext_vector_type(2))) float f32x2;

// d_out layout (floats): [0] loss | [1..8388608] quantized | [8388609] perplexity
//                        | [8388610 ..] encodings (131072 x 512)
// d_ws layout (bytes):
//   [0,2048)         u32 counts[512]
//   [2048]           float loss_acc
//   [4096,6144)      float norms[512]
//   [8192, +512K)    ushort e_bf2[32][4][64][8]  (tile, op{eh0,eh1,el0,el1}, lane, frag)
//                    -> every wave load is a contiguous 1KB (no gathers)

__device__ inline unsigned int bf16_rne(float f) {
    unsigned int u = __float_as_uint(f);
    u += 0x7fffu + ((u >> 16) & 1u);
    return u >> 16;
}

// merge two top-2 lists across lane groups (k-subsets are disjoint)
__device__ inline void merge_top2(float& d1, int& i1, float& d2, int& i2) {
#pragma unroll
    for (int m = 16; m <= 32; m <<= 1) {
        float e1 = __shfl_xor(d1, m), e2 = __shfl_xor(d2, m);
        int j1 = __shfl_xor(i1, m), j2 = __shfl_xor(i2, m);
        bool af = (d1 < e1) || (d1 == e1 && i1 < j1);
        float w2 = af ? d2 : e2; int w2i = af ? i2 : j2;   // winner's runner-up
        float lb = af ? e1 : d1; int lbi = af ? j1 : i1;   // loser's best
        bool bs = (w2 < lb) || (w2 == lb && w2i < lbi);
        d1 = af ? d1 : e1; i1 = af ? i1 : j1;
        d2 = bs ? w2 : lb; i2 = bs ? w2i : lbi;
    }
}

// prep: norms (fp32), fragment-ordered bf16 hi/lo codebook, zero counts/loss.
__global__ __launch_bounds__(256) void vq_prep(const float* __restrict__ emb,
                                               float* __restrict__ norms,
                                               unsigned short* __restrict__ e_bf2,
                                               unsigned int* __restrict__ counts,
                                               float* __restrict__ loss_acc) {
    int gid = blockIdx.x * 256 + threadIdx.x;   // 0..2047
    int tt = gid >> 6, l = gid & 63;
    int nl = l & 15, kg = l >> 4;
    int row = tt * 16 + nl;
    const float* e = emb + row * DIM + kg * 8;  // k-slice 0: kg*8..+8 ; slice 1: +32

    float4 p0 = ((const float4*)e)[0];
    float4 p1 = ((const float4*)e)[1];
    float4 q0 = ((const float4*)(e + 32))[0];
    float4 q1 = ((const float4*)(e + 32))[1];

    float f0[8] = {p0.x, p0.y, p0.z, p0.w, p1.x, p1.y, p1.z, p1.w};
    float f1[8] = {q0.x, q0.y, q0.z, q0.w, q1.x, q1.y, q1.z, q1.w};

    float s = 0.f;
#pragma unroll
    for (int j = 0; j < 8; ++j) s = fmaf(f0[j], f0[j], fmaf(f1[j], f1[j], s));
    s += __shfl_xor(s, 16);
    s += __shfl_xor(s, 32);
    if (kg == 0) norms[row] = s;

    union { bf16x8 v; unsigned int u[4]; } H0, H1, L0, L1;
#pragma unroll
    for (int j = 0; j < 4; ++j) {
        unsigned int h0a = bf16_rne(f0[2 * j]),     h0b = bf16_rne(f0[2 * j + 1]);
        unsigned int h1a = bf16_rne(f1[2 * j]),     h1b = bf16_rne(f1[2 * j + 1]);
        float r0a = f0[2 * j] - __uint_as_float(h0a << 16);
        float r0b = f0[2 * j + 1] - __uint_as_float(h0b << 16);
        float r1a = f1[2 * j] - __uint_as_float(h1a << 16);
        float r1b = f1[2 * j + 1] - __uint_as_float(h1b << 16);
        H0.u[j] = h0a | (h0b << 16);
        H1.u[j] = h1a | (h1b << 16);
        L0.u[j] = bf16_rne(r0a) | (bf16_rne(r0b) << 16);
        L1.u[j] = bf16_rne(r1a) | (bf16_rne(r1b) << 16);
    }
    unsigned short* dst = e_bf2 + (size_t)tt * 8192 + l * 8;
    *(bf16x8*)(dst)        = H0.v;   // eh0
    *(bf16x8*)(dst + 1024) = H1.v;   // eh1
    *(bf16x8*)(dst + 2048) = L0.v;   // el0
    *(bf16x8*)(dst + 3072) = L1.v;   // el1

    if (gid < KCB) counts[gid] = 0u;
    if (gid == 0) *loss_acc = 0.f;
}

// fused: MFMA top-2 argmin with inline zeroing of the block's own encodings
// rows overlapped in the t-loop; exact fp32 rescore; loss, histogram,
// quantized + one-hot writes. Separate tiny vq_final (no device fences).
__global__ __launch_bounds__(256) void vq_fused(const float* __restrict__ x,
                                                const float* __restrict__ emb,
                                                const unsigned short* __restrict__ e_bf2,
                                                const float* __restrict__ norms,
                                                float* __restrict__ out,
                                                unsigned int* __restrict__ counts,
                                                float* __restrict__ loss_acc) {
    float* __restrict__ qout = out + 1;
    float* __restrict__ enc  = out + 8388610;
    int tid = threadIdx.x;
    int wave = tid >> 6;
    int lane = tid & 63;
    int nl = lane & 15, kg = lane >> 4;
    int rowA = blockIdx.x * 128 + wave * 32 + nl;
    int rowB = rowA + 16;

    __shared__ unsigned int hist[KCB];
    __shared__ int2 scand[128];
    __shared__ int sbi[128];
    __shared__ float serr[128];
    for (int j = tid; j < KCB; j += 256) hist[j] = 0u;

    // B-frags (x side): lane col = x-row, k = kg*8+e (+32 per kslice)
    bf16x8 xhA[2], xlA[2], xhB[2], xlB[2];
    {
        const float* xA = x + (size_t)rowA * DIM;
        const float* xB = x + (size_t)rowB * DIM;
#pragma unroll
        for (int ks = 0; ks < 2; ++ks) {
            const float4* pA = (const float4*)(xA + ks * 32 + kg * 8);
            const float4* pB = (const float4*)(xB + ks * 32 + kg * 8);
            float4 a0 = pA[0], a1 = pA[1], b0 = pB[0], b1 = pB[1];
            float fa[8] = {a0.x, a0.y, a0.z, a0.w, a1.x, a1.y, a1.z, a1.w};
            float fb[8] = {b0.x, b0.y, b0.z, b0.w, b1.x, b1.y, b1.z, b1.w};
            union { bf16x8 v; unsigned int u[4]; } HA, LA, HB, LB;
#pragma unroll
            for (int j = 0; j < 4; ++j) {
                unsigned int ha = bf16_rne(fa[2 * j]), hb = bf16_rne(fa[2 * j + 1]);
                unsigned int hc = bf16_rne(fb[2 * j]), hd = bf16_rne(fb[2 * j + 1]);
                float ra = fa[2 * j] - __uint_as_float(ha << 16);
                float rb = fa[2 * j + 1] - __uint_as_float(hb << 16);
                float rc = fb[2 * j] - __uint_as_float(hc << 16);
                float rd = fb[2 * j + 1] - __uint_as_float(hd << 16);
                HA.u[j] = ha | (hb << 16);
                LA.u[j] = bf16_rne(ra) | (bf16_rne(rb) << 16);
                HB.u[j] = hc | (hd << 16);
                LB.u[j] = bf16_rne(rc) | (bf16_rne(rd) << 16);
            }
            xhA[ks] = HA.v; xlA[ks] = LA.v;
            xhB[ks] = HB.v; xlB[ks] = LB.v;
        }
    }

    float d1A = FLT_BIG, d2A = FLT_BIG, d1B = FLT_BIG, d2B = FLT_BIG;
    int i1A = 0, i2A = 0, i1B = 0, i2B = 0;

    // inline zero-fill of this block's 128 encodings rows (256 KB), float4:
    // enc is 8B-aligned; enc+2 is 16B-aligned. head/tail float2 by 2 threads.
    f32x2* enc2 = (f32x2*)enc;
    f32x4* enc4 = (f32x4*)(enc + 2);
    size_t zb4 = (size_t)blockIdx.x * 16384;
    f32x4 z4 = {0.f, 0.f, 0.f, 0.f};
    f32x2 z2 = {0.f, 0.f};
    if (tid == 0)   enc2[(size_t)blockIdx.x * 32768] = z2;
    if (tid == 255) enc2[(size_t)blockIdx.x * 32768 + 32767] = z2;

    // stagger codebook tile order per block to decorrelate L2 pressure
    int t0 = blockIdx.x & 31;
    const unsigned short* ebl = e_bf2 + (size_t)lane * 8;   // lane fragment base
#pragma unroll 2
    for (int t = 0; t < 32; ++t) {
        int tt = (t + t0) & 31;
        const unsigned short* eb = ebl + (size_t)tt * 8192;
        // contiguous 1KB wave loads (coalesced): op strides of 2KB
        bf16x8 eh0 = *(const bf16x8*)(eb);
        bf16x8 eh1 = *(const bf16x8*)(eb + 1024);
        bf16x8 el0 = *(const bf16x8*)(eb + 2048);
        bf16x8 el1 = *(const bf16x8*)(eb + 3072);

        size_t s0 = zb4 + t * 512 + tid;
        enc4[s0] = z4;
        if (!(tid == 255 && t == 31)) enc4[s0 + 256] = z4;   // slot 16383 = tail f32x2

        // split accumulators per kslice: 4 independent 3-deep MFMA chains
        f32x4 aA0 = {}, aA1 = {}, aB0 = {}, aB1 = {};
        aA0 = __builtin_amdgcn_mfma_f32_16x16x32_bf16(eh0, xhA[0], aA0, 0, 0, 0);
        aA1 = __builtin_amdgcn_mfma_f32_16x16x32_bf16(eh1, xhA[1], aA1, 0, 0, 0);
        aB0 = __builtin_amdgcn_mfma_f32_16x16x32_bf16(eh0, xhB[0], aB0, 0, 0, 0);
        aB1 = __builtin_amdgcn_mfma_f32_16x16x32_bf16(eh1, xhB[1], aB1, 0, 0, 0);
        aA0 = __builtin_amdgcn_mfma_f32_16x16x32_bf16(el0, xhA[0], aA0, 0, 0, 0);
        aA1 = __builtin_amdgcn_mfma_f32_16x16x32_bf16(el1, xhA[1], aA1, 0, 0, 0);
        aB0 = __builtin_amdgcn_mfma_f32_16x16x32_bf16(el0, xhB[0], aB0, 0, 0, 0);
        aB1 = __builtin_amdgcn_mfma_f32_16x16x32_bf16(el1, xhB[1], aB1, 0, 0, 0);
        aA0 = __builtin_amdgcn_mfma_f32_16x16x32_bf16(eh0, xlA[0], aA0, 0, 0, 0);
        aA1 = __builtin_amdgcn_mfma_f32_16x16x32_bf16(eh1, xlA[1], aA1, 0, 0, 0);
        aB0 = __builtin_amdgcn_mfma_f32_16x16x32_bf16(eh0, xlB[0], aB0, 0, 0, 0);
        aB1 = __builtin_amdgcn_mfma_f32_16x16x32_bf16(eh1, xlB[1], aB1, 0, 0, 0);

        // C/D: col=lane&15 (x-row), row=(lane>>4)*4+reg (e-idx) [m89-verified]
        int krow0 = tt * 16 + kg * 4;
        f32x4 nv = *(const f32x4*)(norms + krow0);
#pragma unroll
        for (int r = 0; r < 4; ++r) {
            float en = nv[r];
            int ki = krow0 + r;
            float dA = fmaf(-2.f, aA0[r] + aA1[r], en);   // xn dropped: row-constant
            bool c1 = dA < d1A, c2 = dA < d2A;
            d2A = c1 ? d1A : (c2 ? dA : d2A);
            i2A = c1 ? i1A : (c2 ? ki : i2A);
            d1A = c1 ? dA : d1A;
            i1A = c1 ? ki : i1A;
            float dB = fmaf(-2.f, aB0[r] + aB1[r], en);
            bool e1c = dB < d1B, e2c = dB < d2B;
            d2B = e1c ? d1B : (e2c ? dB : d2B);
            i2B = e1c ? i1B : (e2c ? ki : i2B);
            d1B = e1c ? dB : d1B;
            i1B = e1c ? ki : i1B;
        }
    }

    merge_top2(d1A, i1A, d2A, i2A);
    merge_top2(d1B, i1B, d2B, i2B);
    if (lane < 16) {
        scand[wave * 32 + nl] = make_int2(i1A, i2A);
        scand[wave * 32 + nl + 16] = make_int2(i1B, i2B);
    }
    __syncthreads();   // drains the zero stores too (vmcnt(0) before s_barrier)

    // ---- exact fp32 rescore: one thread per row, STREAMED (low VGPR)
    if (tid < 128) {
        int grow = blockIdx.x * 128 + tid;
        int2 cd = scand[tid];
        const float4* xr = (const float4*)(x + (size_t)grow * DIM);
        const float4* eA = (const float4*)(emb + (size_t)cd.x * DIM);
        const float4* eB = (const float4*)(emb + (size_t)cd.y * DIM);

        float n0 = 0.f, n1 = 0.f, n2 = 0.f, n3 = 0.f;
        float a0 = 0.f, a1 = 0.f, a2 = 0.f, a3 = 0.f;
        float b0 = 0.f, b1 = 0.f, b2 = 0.f, b3 = 0.f;
#pragma unroll
        for (int j = 0; j < 16; ++j) {
            float4 xv = xr[j];
            float4 ev = eA[j], fv = eB[j];
            n0 = fmaf(xv.x, xv.x, n0);
            n1 = fmaf(xv.y, xv.y, n1);
            n2 = fmaf(xv.z, xv.z, n2);
            n3 = fmaf(xv.w, xv.w, n3);
            a0 = fmaf(xv.x, ev.x, a0);
            a1 = fmaf(xv.y, ev.y, a1);
            a2 = fmaf(xv.z, ev.z, a2);
            a3 = fmaf(xv.w, ev.w, a3);
            b0 = fmaf(xv.x, fv.x, b0);
            b1 = fmaf(xv.y, fv.y, b1);
            b2 = fmaf(xv.z, fv.z, b2);
            b3 = fmaf(xv.w, fv.w, b3);
        }
        float xn = (n0 + n1) + (n2 + n3);
        float dotA = (a0 + a1) + (a2 + a3);
        float dotB = (b0 + b1) + (b2 + b3);
        float dA = fmaf(-2.f, dotA, xn) + norms[cd.x];
        float dB = fmaf(-2.f, dotB, xn) + norms[cd.y];
        // np.argmin keeps FIRST minimum -> ties to smaller index
        int bi = (dB < dA || (dB == dA && cd.y < cd.x)) ? cd.y : cd.x;

        // err pass: sum (x - e_bi)^2
        const float4* ebv = (const float4*)(emb + (size_t)bi * DIM);
        float c0 = 0.f, c1 = 0.f, c2 = 0.f, c3 = 0.f;
#pragma unroll
        for (int j = 0; j < 16; ++j) {
            float4 xv = xr[j];
            float4 ev = ebv[j];
            float e0 = xv.x - ev.x, e1 = xv.y - ev.y;
            float e2 = xv.z - ev.z, e3 = xv.w - ev.w;
            c0 = fmaf(e0, e0, c0);
            c1 = fmaf(e1, e1, c1);
            c2 = fmaf(e2, e2, c2);
            c3 = fmaf(e3, e3, c3);
        }
        float err = (c0 + c1) + (c2 + c3);

        sbi[tid] = bi;
        serr[tid] = err;
        atomicAdd(&hist[bi], 1u);
        // one-hot: this block zeroed this entire row before the barrier
        enc[(size_t)grow * KCB + bi] = 1.0f;
    }
    __syncthreads();

    // flush histogram
    for (int j = tid; j < KCB; j += 256) {
        unsigned int c = hist[j];
        if (c) atomicAdd(&counts[j], c);
    }
    // loss reduction over 128 row errors
    if (tid < 64) {
        float v = serr[tid] + serr[tid + 64];
#pragma unroll
        for (int off = 32; off > 0; off >>= 1) v += __shfl_down(v, off);
        if (tid == 0) atomicAdd(loss_acc, v);
    }
    // cooperative quantized write (dword stores; qout = out+1, 4B-aligned)
#pragma unroll 4
    for (int j = 0; j < 32; ++j) {
        int f = j * 256 + tid;          // 0..8191
        int r = f >> 6, c = f & 63;
        qout[((size_t)blockIdx.x * 128 + r) * DIM + c] =
            emb[(size_t)sbi[r] * DIM + c];
    }
}

__global__ __launch_bounds__(512) void vq_final(const unsigned int* __restrict__ counts,
                                                const float* __restrict__ loss_acc,
                                                float* __restrict__ out) {
    __shared__ float red[512];
    int t = threadIdx.x;
    float p = (float)counts[t] * (1.0f / 131072.0f);
    red[t] = p * logf(p + 1e-10f);
    __syncthreads();
    for (int s = 256; s > 0; s >>= 1) {
        if (t < s) red[t] += red[t + s];
        __syncthreads();
    }
    if (t == 0) {
        out[8388609] = expf(-red[0]);
        out[0] = 1.25f * (*loss_acc) * (1.0f / 8388608.0f);
    }
}

extern "C" void kernel_launch(void* const* d_in, const int* in_sizes, int n_in,
                              void* d_out, int out_size, void* d_ws, size_t ws_size,
                              hipStream_t stream) {
    const float* x   = (const float*)d_in[0];
    const float* emb = (const float*)d_in[1];
    float* out = (float*)d_out;
    char* ws = (char*)d_ws;
    unsigned int* counts = (unsigned int*)ws;
    float* loss_acc = (float*)(ws + 2048);
    float* norms = (float*)(ws + 4096);
    unsigned short* e_bf2 = (unsigned short*)(ws + 8192);

    vq_prep<<<8, 256, 0, stream>>>(emb, norms, e_bf2, counts, loss_acc);
    vq_fused<<<1024, 256, 0, stream>>>(x, emb, e_bf2, norms, out, counts, loss_acc);
    vq_final<<<1, 512, 0, stream>>>(counts, loss_acc, out);
}